// Round 2
// baseline (1346.543 us; speedup 1.0000x reference)
//
#include <hip/hip_runtime.h>

#define N_PTS 65536
#define M_PTS 65536
#define K_NB  16
#define CP    68          // packed channels: 64 feat + 3 relpos + 1 pad
#define TS    69          // pack_points LDS tile stride (odd -> conflict-free)

// ---- pack x[64][N] + pos[3][N] -> P[N][68] fp32 (contiguous per point) ----
__global__ __launch_bounds__(256) void pack_points(
    const float* __restrict__ x,
    const float* __restrict__ pos,
    float* __restrict__ P) {
  __shared__ float tile[256 * TS];
  const int t  = threadIdx.x;
  const int n0 = blockIdx.x * 256;
  #pragma unroll 4
  for (int c = 0; c < 64; ++c) tile[t * TS + c] = x[(size_t)c * N_PTS + n0 + t];
  #pragma unroll
  for (int d = 0; d < 3; ++d) tile[t * TS + 64 + d] = pos[(size_t)d * N_PTS + n0 + t];
  tile[t * TS + 67] = 0.f;
  __syncthreads();
  float* Pd = P + (size_t)n0 * CP;
  #pragma unroll 2
  for (int i = 0; i < CP; ++i) {            // 68 coalesced dwords per point
    const int d  = t + i * 256;             // 0 .. 256*68-1
    const int nl = d / CP;
    const int c  = d - nl * CP;
    Pd[d] = tile[nl * TS + c];
  }
}

// ---- fused gather + MLP(67->64 relu) + MLP(64->128) + max over K ----
template <bool PACKED>
__global__ __launch_bounds__(256) void pointnet_fused(
    const float* __restrict__ P,      // [N][68] (PACKED only)
    const float* __restrict__ x,      // [64][N] (direct only)
    const float* __restrict__ pos,    // [3][N]  (direct only)
    const float* __restrict__ sup,    // [3][M]
    const float* __restrict__ W1,     // [64][67]
    const float* __restrict__ b1,     // [64]
    const float* __restrict__ W2,     // [128][64]
    const float* __restrict__ b2,     // [128]
    const int* __restrict__ indices,  // [M][16]
    float* __restrict__ out) {        // [128][M]
  __shared__ float sfeat[K_NB][CP];   // 16 x 68 gathered features
  __shared__ float shid[K_NB][64];    // hidden after relu
  __shared__ float smax[4][128];
  __shared__ int sidx[K_NB];

  const int t = threadIdx.x;
  const int m = blockIdx.x;

  if (t < K_NB) sidx[t] = indices[m * K_NB + t];
  const float sup0 = sup[m];
  const float sup1 = sup[M_PTS + m];
  const float sup2 = sup[2 * M_PTS + m];
  __syncthreads();

  // gather: 16 rows x 17 float4 units
  for (int u = t; u < K_NB * 17; u += 256) {
    const int k  = u / 17;
    const int c4 = (u - k * 17) * 4;
    const int idx = sidx[k];
    float4 w;
    if (PACKED) {
      const float4 v = *(const float4*)(P + (size_t)idx * CP + c4);
      w = v;
      if (c4 == 64) { w.x = v.x - sup0; w.y = v.y - sup1; w.z = v.z - sup2; w.w = 0.f; }
    } else {
      if (c4 < 64) {
        w.x = x[(size_t)(c4 + 0) * N_PTS + idx];
        w.y = x[(size_t)(c4 + 1) * N_PTS + idx];
        w.z = x[(size_t)(c4 + 2) * N_PTS + idx];
        w.w = x[(size_t)(c4 + 3) * N_PTS + idx];
      } else {
        w.x = pos[idx] - sup0;
        w.y = pos[N_PTS + idx] - sup1;
        w.z = pos[2 * N_PTS + idx] - sup2;
        w.w = 0.f;
      }
    }
    *(float4*)&sfeat[k][c4] = w;
  }

  // ---- stage 1: hidden[k][h] = relu(W1 . feat[k] + b1) ----
  const int h  = t & 63;
  const int kg = t >> 6;              // 4 groups of 4 neighbors

  float w1r[CP];
  #pragma unroll
  for (int c = 0; c < 67; ++c) w1r[c] = W1[h * 67 + c];
  w1r[67] = 0.f;
  const float bias1 = b1[h];
  __syncthreads();   // sfeat ready

  float a0 = bias1, a1 = bias1, a2 = bias1, a3 = bias1;
  const float4* r0 = (const float4*)sfeat[kg * 4 + 0];
  const float4* r1 = (const float4*)sfeat[kg * 4 + 1];
  const float4* r2 = (const float4*)sfeat[kg * 4 + 2];
  const float4* r3 = (const float4*)sfeat[kg * 4 + 3];
  #pragma unroll
  for (int q = 0; q < 17; ++q) {      // 17 chunks of 4 channels (broadcast reads)
    const float4 v0 = r0[q], v1 = r1[q], v2 = r2[q], v3 = r3[q];
    #define STEP1(COMP, J) { \
      const float w = w1r[q * 4 + (J)]; \
      a0 += w * v0.COMP; a1 += w * v1.COMP; a2 += w * v2.COMP; a3 += w * v3.COMP; }
    STEP1(x, 0) STEP1(y, 1) STEP1(z, 2) STEP1(w, 3)
    #undef STEP1
  }
  shid[kg * 4 + 0][h] = fmaxf(a0, 0.f);
  shid[kg * 4 + 1][h] = fmaxf(a1, 0.f);
  shid[kg * 4 + 2][h] = fmaxf(a2, 0.f);
  shid[kg * 4 + 3][h] = fmaxf(a3, 0.f);

  // ---- stage 2: out2[o][k] = W2 . hidden[k]; max over k ----
  const int ow = t & 63;              // handles o = ow and ow+64
  float w2a[64], w2b[64];
  #pragma unroll
  for (int hh = 0; hh < 64; ++hh) {
    w2a[hh] = W2[ow * 64 + hh];
    w2b[hh] = W2[(ow + 64) * 64 + hh];
  }
  __syncthreads();   // shid ready

  float mxa = -3.0e38f, mxb = -3.0e38f;
  #pragma unroll
  for (int j = 0; j < 4; ++j) {
    const int k = kg * 4 + j;
    const float4* hr = (const float4*)shid[k];
    float pa = 0.f, pb = 0.f;
    #pragma unroll
    for (int q = 0; q < 16; ++q) {    // 16 chunks of 4 hidden (broadcast reads)
      const float4 v = hr[q];
      #define STEP2(COMP, J) { \
        pa += w2a[q * 4 + (J)] * v.COMP; \
        pb += w2b[q * 4 + (J)] * v.COMP; }
      STEP2(x, 0) STEP2(y, 1) STEP2(z, 2) STEP2(w, 3)
      #undef STEP2
    }
    mxa = fmaxf(mxa, pa);
    mxb = fmaxf(mxb, pb);
  }
  smax[kg][ow] = mxa;
  smax[kg][64 + ow] = mxb;
  __syncthreads();

  if (t < 128) {
    const float r = fmaxf(fmaxf(smax[0][t], smax[1][t]),
                          fmaxf(smax[2][t], smax[3][t])) + b2[t];
    out[(size_t)t * M_PTS + m] = r;
  }
}

extern "C" void kernel_launch(void* const* d_in, const int* in_sizes, int n_in,
                              void* d_out, int out_size, void* d_ws, size_t ws_size,
                              hipStream_t stream) {
  const float* x   = (const float*)d_in[0];
  const float* pos = (const float*)d_in[1];
  const float* sup = (const float*)d_in[2];
  const float* W1  = (const float*)d_in[3];
  const float* b1  = (const float*)d_in[4];
  const float* W2  = (const float*)d_in[5];
  const float* b2  = (const float*)d_in[6];
  const int* indices = (const int*)d_in[7];
  float* out = (float*)d_out;

  const size_t p_bytes = (size_t)N_PTS * CP * sizeof(float);   // 17.8 MB
  if (ws_size >= p_bytes) {
    float* P = (float*)d_ws;
    pack_points<<<N_PTS / 256, 256, 0, stream>>>(x, pos, P);
    pointnet_fused<true><<<M_PTS, 256, 0, stream>>>(
        P, x, pos, sup, W1, b1, W2, b2, indices, out);
  } else {
    pointnet_fused<false><<<M_PTS, 256, 0, stream>>>(
        nullptr, x, pos, sup, W1, b1, W2, b2, indices, out);
  }
}

// Round 3
// 151.468 us; speedup vs baseline: 8.8900x; 8.8900x over previous
//
#include <hip/hip_runtime.h>

#define NPTS 65536
#define MPTS 65536

typedef __attribute__((ext_vector_type(8))) short bf16x8;
typedef __attribute__((ext_vector_type(4))) float f32x4;

__device__ __forceinline__ float bflo(unsigned int u){ union{unsigned int i; float f;} v; v.i = u<<16; return v.f; }
__device__ __forceinline__ float bfhi(unsigned int u){ union{unsigned int i; float f;} v; v.i = u & 0xffff0000u; return v.f; }
__device__ __forceinline__ unsigned short f2bf(float f){
  union{float f; unsigned int i;} v; v.f=f;
  unsigned int r = v.i + 0x7fffu + ((v.i>>16)&1u);  // RNE
  return (unsigned short)(r>>16);
}

// ---- pack x[64][N] + pos[3][N] -> P2[N][72] bf16 (per-point contiguous) ----
__global__ __launch_bounds__(256) void pack_points(
    const float* __restrict__ x, const float* __restrict__ pos,
    unsigned short* __restrict__ P2) {
  __shared__ unsigned short tile[256 * 72];
  const int t = threadIdx.x;
  const int n0 = blockIdx.x * 256;
  #pragma unroll 8
  for (int c = 0; c < 64; ++c) tile[t*72 + c] = f2bf(x[(size_t)c * NPTS + n0 + t]);
  #pragma unroll
  for (int d = 0; d < 3; ++d) tile[t*72 + 64 + d] = f2bf(pos[(size_t)d * NPTS + n0 + t]);
  #pragma unroll
  for (int c = 67; c < 72; ++c) tile[t*72 + c] = 0;
  __syncthreads();
  const unsigned int* tD = (const unsigned int*)tile;
  unsigned int* pD = (unsigned int*)P2 + (size_t)n0 * 36;
  #pragma unroll 4
  for (int i = 0; i < 36; ++i) pD[t + i*256] = tD[t + i*256];   // flat copy: conflict-free, coalesced
}

// ---- pack W1[64][67], W2[128][64] into MFMA lane-fragment images (bf16) ----
// W1F frag(kt,nt,lane): 8 bf16 = W1[nt*16+(lane&15)][kt*32+(lane>>4)*8+j], 0 if c>=67
// W2F frag(kt,ot,lane): 8 bf16 = W2[ot*16+(lane&15)][kt*32+(lane>>4)*8+j]
__global__ __launch_bounds__(256) void pack_wf(
    const float* __restrict__ W1, const float* __restrict__ W2,
    unsigned short* __restrict__ W1F, unsigned short* __restrict__ W2F) {
  const int f = blockIdx.x * 256 + threadIdx.x;
  if (f < 768) {
    const int kt = f >> 8, rem = f & 255, nt = rem >> 6, lane = rem & 63;
    const int h = nt*16 + (lane & 15);
    const int c0 = kt*32 + (lane >> 4) * 8;
    #pragma unroll
    for (int j = 0; j < 8; ++j) {
      const int c = c0 + j;
      W1F[f*8 + j] = (c < 67) ? f2bf(W1[h*67 + c]) : (unsigned short)0;
    }
  } else if (f < 1792) {
    const int g = f - 768;
    const int kt = g >> 9, rem = g & 511, ot = rem >> 6, lane = rem & 63;
    const int o = ot*16 + (lane & 15);
    const int h0 = kt*32 + (lane >> 4) * 8;
    #pragma unroll
    for (int j = 0; j < 8; ++j) W2F[g*8 + j] = f2bf(W2[o*64 + h0 + j]);
  }
}

#define MFMA16(a,b,c) __builtin_amdgcn_mfma_f32_16x16x32_bf16((a),(b),(c),0,0,0)

// ---- fused: gather -> MLP1(relu) -> MLP2 -> max over K, 16 m's per block ----
__global__ __launch_bounds__(256, 2) void pointnet_mfma(
    const unsigned short* __restrict__ P2,   // [N][72] bf16
    const float* __restrict__ sup,           // [3][M] fp32
    const unsigned short* __restrict__ W1F,  // frag image
    const float* __restrict__ b1,
    const unsigned short* __restrict__ W2F,  // frag image
    const float* __restrict__ b2,
    const int* __restrict__ indices,         // [M][16]
    float* __restrict__ out) {               // [128][M] fp32
  __shared__ __align__(16) char smem[53248];
  unsigned short* featB = (unsigned short*)smem;    // [256][104] bf16 (cols 0..95 = K-padded features)
  unsigned short* hlds  = (unsigned short*)smem;    // [256][72]  bf16 (overlay, post-stage1)
  float* smax = (float*)(smem + 40960);             // [16][128]  fp32

  const int t = threadIdx.x;
  const int m0 = blockIdx.x * 16;
  const int lane = t & 63, w = t >> 6, quad = lane >> 4, lr = lane & 15;

  // ---- gather: thread t owns point t ----
  {
    const int idx = indices[m0*16 + t];
    const uint4* src = (const uint4*)(P2 + (size_t)idx * 72);
    uint4* dst = (uint4*)(featB + t * 104);
    uint4 u[9];
    #pragma unroll
    for (int i = 0; i < 9; ++i) u[i] = src[i];
    const int mm = m0 + (t >> 4);
    const float s0 = sup[mm], s1 = sup[MPTS + mm], s2 = sup[2*MPTS + mm];
    const float p0 = bflo(u[8].x), p1 = bfhi(u[8].x), p2 = bflo(u[8].y);
    u[8].x = (unsigned int)f2bf(p0 - s0) | ((unsigned int)f2bf(p1 - s1) << 16);
    u[8].y = (unsigned int)f2bf(p2 - s2);
    u[8].z = 0u; u[8].w = 0u;
    #pragma unroll
    for (int i = 0; i < 9; ++i) dst[i] = u[i];
    const uint4 z = {0u, 0u, 0u, 0u};
    dst[9] = z; dst[10] = z; dst[11] = z;   // zero channels 72..95
  }

  // W1 fragments + bias (global, L1/L2-hot) while the gather lands
  bf16x8 w1f[3][4];
  #pragma unroll
  for (int kt = 0; kt < 3; ++kt)
    #pragma unroll
    for (int nt = 0; nt < 4; ++nt)
      w1f[kt][nt] = ((const bf16x8*)W1F)[(kt*4 + nt)*64 + lane];
  float b1s[4];
  #pragma unroll
  for (int nt = 0; nt < 4; ++nt) b1s[nt] = b1[nt*16 + lr];

  __syncthreads();   // featB ready

  // ---- stage 1: D1[point][h] ; A=feat rows (m=point), B=W1 frags (n=h) ----
  const f32x4 fz = {0.f, 0.f, 0.f, 0.f};
  f32x4 acc[4][4];
  #pragma unroll
  for (int pt = 0; pt < 4; ++pt)
    #pragma unroll
    for (int nt = 0; nt < 4; ++nt) acc[pt][nt] = fz;
  #pragma unroll
  for (int kt = 0; kt < 3; ++kt) {
    bf16x8 af[4];
    #pragma unroll
    for (int pt = 0; pt < 4; ++pt)
      af[pt] = *(const bf16x8*)&featB[(w*64 + pt*16 + lr)*104 + kt*32 + quad*8];
    #pragma unroll
    for (int pt = 0; pt < 4; ++pt)
      #pragma unroll
      for (int nt = 0; nt < 4; ++nt)
        acc[pt][nt] = MFMA16(af[pt], w1f[kt][nt], acc[pt][nt]);
  }

  __syncthreads();   // all featB reads done before overlay write

  // relu(bias) -> hlds[point][h] bf16
  #pragma unroll
  for (int pt = 0; pt < 4; ++pt)
    #pragma unroll
    for (int nt = 0; nt < 4; ++nt) {
      const int h = nt*16 + lr;
      #pragma unroll
      for (int r = 0; r < 4; ++r) {
        const int p = w*64 + pt*16 + quad*4 + r;
        hlds[p*72 + h] = f2bf(fmaxf(acc[pt][nt][r] + b1s[nt], 0.f));
      }
    }
  __syncthreads();

  // ---- stage 2: D2[point][o], two halves of o; k-max per 16-point tile ----
  #pragma unroll
  for (int oh = 0; oh < 2; ++oh) {
    bf16x8 w2f[2][4];
    #pragma unroll
    for (int kt = 0; kt < 2; ++kt)
      #pragma unroll
      for (int ot = 0; ot < 4; ++ot)
        w2f[kt][ot] = ((const bf16x8*)W2F)[(kt*8 + oh*4 + ot)*64 + lane];
    f32x4 a2[4][4];
    #pragma unroll
    for (int pt = 0; pt < 4; ++pt)
      #pragma unroll
      for (int ot = 0; ot < 4; ++ot) a2[pt][ot] = fz;
    #pragma unroll
    for (int kt = 0; kt < 2; ++kt) {
      bf16x8 ah[4];
      #pragma unroll
      for (int pt = 0; pt < 4; ++pt)
        ah[pt] = *(const bf16x8*)&hlds[(w*64 + pt*16 + lr)*72 + kt*32 + quad*8];
      #pragma unroll
      for (int pt = 0; pt < 4; ++pt)
        #pragma unroll
        for (int ot = 0; ot < 4; ++ot)
          a2[pt][ot] = MFMA16(ah[pt], w2f[kt][ot], a2[pt][ot]);
    }
    #pragma unroll
    for (int pt = 0; pt < 4; ++pt)
      #pragma unroll
      for (int ot = 0; ot < 4; ++ot) {
        f32x4 v4 = a2[pt][ot];
        float v = fmaxf(fmaxf(v4[0], v4[1]), fmaxf(v4[2], v4[3]));  // max over r (4 points)
        v = fmaxf(v, __shfl_xor(v, 16));                            // across quads
        v = fmaxf(v, __shfl_xor(v, 32));
        if (quad == 0) smax[(w*4 + pt)*128 + oh*64 + ot*16 + lr] = v;
      }
  }
  __syncthreads();

  // ---- coalesced store: out[o][m0..m0+15] ----
  #pragma unroll
  for (int i = 0; i < 2; ++i) {
    const int u = t + i*256;
    const int o = u >> 2, mg = u & 3;
    const float bb = b2[o];
    float4 val;
    val.x = smax[(mg*4 + 0)*128 + o] + bb;
    val.y = smax[(mg*4 + 1)*128 + o] + bb;
    val.z = smax[(mg*4 + 2)*128 + o] + bb;
    val.w = smax[(mg*4 + 3)*128 + o] + bb;
    *(float4*)(out + (size_t)o * MPTS + m0 + mg*4) = val;
  }
}

// ---- fallback (ws too small): round-2 direct fp32 kernel, known-correct ----
__global__ __launch_bounds__(256) void pointnet_fallback(
    const float* __restrict__ x, const float* __restrict__ pos,
    const float* __restrict__ sup,
    const float* __restrict__ W1, const float* __restrict__ b1,
    const float* __restrict__ W2, const float* __restrict__ b2,
    const int* __restrict__ indices, float* __restrict__ out) {
  __shared__ float sfeat[16][68];
  __shared__ float shid[16][64];
  __shared__ float smax[4][128];
  __shared__ int sidx[16];
  const int t = threadIdx.x;
  const int m = blockIdx.x;
  if (t < 16) sidx[t] = indices[m*16 + t];
  const float sup0 = sup[m], sup1 = sup[MPTS + m], sup2 = sup[2*MPTS + m];
  __syncthreads();
  for (int u = t; u < 16*17; u += 256) {
    const int k = u / 17, c4 = (u - k*17) * 4;
    const int idx = sidx[k];
    float4 w;
    if (c4 < 64) {
      w.x = x[(size_t)(c4+0)*NPTS + idx]; w.y = x[(size_t)(c4+1)*NPTS + idx];
      w.z = x[(size_t)(c4+2)*NPTS + idx]; w.w = x[(size_t)(c4+3)*NPTS + idx];
    } else {
      w.x = pos[idx] - sup0; w.y = pos[NPTS + idx] - sup1;
      w.z = pos[2*NPTS + idx] - sup2; w.w = 0.f;
    }
    *(float4*)&sfeat[k][c4] = w;
  }
  const int h = t & 63, kg = t >> 6;
  float w1r[68];
  #pragma unroll
  for (int c = 0; c < 67; ++c) w1r[c] = W1[h*67 + c];
  w1r[67] = 0.f;
  const float bias1 = b1[h];
  __syncthreads();
  #pragma unroll
  for (int j = 0; j < 4; ++j) {
    const int k = kg*4 + j;
    float a = bias1;
    const float4* rr = (const float4*)sfeat[k];
    #pragma unroll
    for (int q = 0; q < 17; ++q) {
      const float4 v = rr[q];
      a += w1r[q*4+0]*v.x + w1r[q*4+1]*v.y + w1r[q*4+2]*v.z + w1r[q*4+3]*v.w;
    }
    shid[k][h] = fmaxf(a, 0.f);
  }
  const int ow = t & 63;
  float w2a[64], w2b[64];
  #pragma unroll
  for (int hh = 0; hh < 64; ++hh) { w2a[hh] = W2[ow*64 + hh]; w2b[hh] = W2[(ow+64)*64 + hh]; }
  __syncthreads();
  float mxa = -3.0e38f, mxb = -3.0e38f;
  #pragma unroll
  for (int j = 0; j < 4; ++j) {
    const int k = kg*4 + j;
    const float4* hr = (const float4*)shid[k];
    float pa = 0.f, pb = 0.f;
    #pragma unroll
    for (int q = 0; q < 16; ++q) {
      const float4 v = hr[q];
      pa += w2a[q*4+0]*v.x + w2a[q*4+1]*v.y + w2a[q*4+2]*v.z + w2a[q*4+3]*v.w;
      pb += w2b[q*4+0]*v.x + w2b[q*4+1]*v.y + w2b[q*4+2]*v.z + w2b[q*4+3]*v.w;
    }
    mxa = fmaxf(mxa, pa); mxb = fmaxf(mxb, pb);
  }
  smax[kg][ow] = mxa; smax[kg][64 + ow] = mxb;
  __syncthreads();
  if (t < 128) {
    out[(size_t)t * MPTS + m] =
        fmaxf(fmaxf(smax[0][t], smax[1][t]), fmaxf(smax[2][t], smax[3][t])) + b2[t];
  }
}

extern "C" void kernel_launch(void* const* d_in, const int* in_sizes, int n_in,
                              void* d_out, int out_size, void* d_ws, size_t ws_size,
                              hipStream_t stream) {
  const float* x   = (const float*)d_in[0];
  const float* pos = (const float*)d_in[1];
  const float* sup = (const float*)d_in[2];
  const float* W1  = (const float*)d_in[3];
  const float* b1  = (const float*)d_in[4];
  const float* W2  = (const float*)d_in[5];
  const float* b2  = (const float*)d_in[6];
  const int* indices = (const int*)d_in[7];
  float* out = (float*)d_out;

  const size_t P2_BYTES  = (size_t)NPTS * 72 * 2;        // 9,437,184
  const size_t W1F_BYTES = 768 * 8 * 2;                  // 12,288
  const size_t W2F_BYTES = 1024 * 8 * 2;                 // 16,384
  if (ws_size >= P2_BYTES + W1F_BYTES + W2F_BYTES) {
    unsigned short* P2  = (unsigned short*)d_ws;
    unsigned short* W1F = (unsigned short*)((char*)d_ws + P2_BYTES);
    unsigned short* W2F = (unsigned short*)((char*)d_ws + P2_BYTES + W1F_BYTES);
    pack_points<<<NPTS/256, 256, 0, stream>>>(x, pos, P2);
    pack_wf<<<7, 256, 0, stream>>>(W1, W2, W1F, W2F);
    pointnet_mfma<<<MPTS/16, 256, 0, stream>>>(P2, sup, W1F, b1, W2F, b2, indices, out);
  } else {
    pointnet_fallback<<<MPTS, 256, 0, stream>>>(x, pos, sup, W1, b1, W2, b2, indices, out);
  }
}